// Round 8
// baseline (253.378 us; speedup 1.0000x reference)
//
#include <hip/hip_runtime.h>

#define N_NODES 50000
#define N_EDGES 800000
#define DIM 128
#define KTOT 256        // [agg | x] concatenated along k
#define N_GRAPHS 64
#define BUCKET_CAP 64
#define LSTR 264        // LDS A-tile row stride in bf16 (+8 pad)

// edge binning: bin = dst>>7 (128 nodes/bin)
#define NBINS 391       // ceil(50000/128)
#define BINCAP2 2816    // per-bin list capacity (mean 2046, +17 sigma)
#define N_NODES_PAD (NBINS * 128)   // 50048

// bin1 geometry: 512 thr x 8 edges = 4096 edges/block -> 196 blocks
#define BIN1_TPB 512
#define BIN1_EPT 8
#define BIN1_EPB (BIN1_TPB * BIN1_EPT)
#define BIN1_GRID ((N_EDGES + BIN1_EPB - 1) / BIN1_EPB)

typedef __attribute__((ext_vector_type(8))) short bf16x8;
typedef __attribute__((ext_vector_type(16))) float f32x16;

__device__ __forceinline__ float bf2f(unsigned int u16) {
    return __uint_as_float(u16 << 16);
}
__device__ __forceinline__ unsigned short f2bf(float f) {
    unsigned int v = __float_as_uint(f);
    unsigned int r = (v + 0x7fffu + ((v >> 16) & 1u)) >> 16;   // RNE
    return (unsigned short)r;
}

// ---------- setup: casts ----------
// also zeros bincnt (must run before bin1_kernel)
__global__ void castx_kernel(const float* __restrict__ x, ushort* __restrict__ xb,
                             int* __restrict__ bincnt) {
    int i = blockIdx.x * blockDim.x + threadIdx.x;   // float4 index
    if (i < NBINS) bincnt[i] = 0;
    if (i >= N_NODES * DIM / 4) return;
    float4 v = ((const float4*)x)[i];
    ushort4 o;
    o.x = f2bf(v.x); o.y = f2bf(v.y); o.z = f2bf(v.z); o.w = f2bf(v.w);
    ((ushort4*)xb)[i] = o;
}

// wb layout per layer: [128 j][256 k] with k<128 = Wl, k>=128 = Wr. Also zeros pool.
__global__ void castw_kernel(const float* __restrict__ Wl0, const float* __restrict__ Wr0,
                             const float* __restrict__ Wl1, const float* __restrict__ Wr1,
                             const float* __restrict__ Wl2, const float* __restrict__ Wr2,
                             ushort* __restrict__ wb, float* __restrict__ pool) {
    int id = blockIdx.x * blockDim.x + threadIdx.x;   // 3*128*256 = 98304
    if (id < N_GRAPHS * DIM) pool[id] = 0.f;
    if (id >= 3 * DIM * KTOT) return;
    int l = id >> 15;
    int r = id & 32767;
    int j = r >> 8, k = r & 255;
    const float* Wl = (l == 0) ? Wl0 : (l == 1) ? Wl1 : Wl2;
    const float* Wr = (l == 0) ? Wr0 : (l == 1) ? Wr1 : Wr2;
    float v = (k < DIM) ? Wl[j * DIM + k] : Wr[j * DIM + k - DIM];
    wb[id] = f2bf(v);
}

// ---------- edge binning phase 1: LDS-ranked block partition ----------
__global__ __launch_bounds__(BIN1_TPB) void bin1_kernel(
    const int* __restrict__ src, const int* __restrict__ dst,
    int* __restrict__ bincnt, uint* __restrict__ binbuf) {
    __shared__ uint hist[NBINS];
    __shared__ uint gbase[NBINS];
    const int tid = threadIdx.x;
    for (int i = tid; i < NBINS; i += BIN1_TPB) hist[i] = 0;
    __syncthreads();

    const int e0 = blockIdx.x * BIN1_EPB + tid * BIN1_EPT;
    uint val[BIN1_EPT];
    int  bin[BIN1_EPT];
    uint rk[BIN1_EPT];

    if (e0 + BIN1_EPT <= N_EDGES) {
        int4 s0 = *(const int4*)(src + e0);
        int4 s1 = *(const int4*)(src + e0 + 4);
        int4 d0 = *(const int4*)(dst + e0);
        int4 d1 = *(const int4*)(dst + e0 + 4);
        int ss[8] = {s0.x, s0.y, s0.z, s0.w, s1.x, s1.y, s1.z, s1.w};
        int dd[8] = {d0.x, d0.y, d0.z, d0.w, d1.x, d1.y, d1.z, d1.w};
        #pragma unroll
        for (int i = 0; i < BIN1_EPT; ++i) {
            bin[i] = dd[i] >> 7;
            val[i] = (uint)ss[i] | ((uint)(dd[i] & 127) << 16);
            rk[i]  = atomicAdd(&hist[bin[i]], 1u);
        }
    } else {
        #pragma unroll
        for (int i = 0; i < BIN1_EPT; ++i) {
            if (e0 + i < N_EDGES) {
                int s = src[e0 + i], d = dst[e0 + i];
                bin[i] = d >> 7;
                val[i] = (uint)s | ((uint)(d & 127) << 16);
                rk[i]  = atomicAdd(&hist[bin[i]], 1u);
            } else {
                bin[i] = -1; val[i] = 0; rk[i] = 0;
            }
        }
    }
    __syncthreads();

    for (int i = tid; i < NBINS; i += BIN1_TPB)
        gbase[i] = (uint)atomicAdd(&bincnt[i], (int)hist[i]);
    __syncthreads();

    #pragma unroll
    for (int i = 0; i < BIN1_EPT; ++i) {
        if (bin[i] >= 0) {
            uint pos = gbase[bin[i]] + rk[i];
            if (pos < BINCAP2)
                binbuf[(size_t)bin[i] * BINCAP2 + pos] = val[i];
        }
    }
}

// ---------- edge binning phase 2: LDS bucket build, coalesced flush ----------
__global__ __launch_bounds__(256) void bin2_kernel(
    const uint* __restrict__ binbuf, const int* __restrict__ bincnt,
    ushort* __restrict__ bucket, int* __restrict__ cnt) {
    __shared__ int lcnt[128];
    __shared__ ushort lbuck[128 * BUCKET_CAP];   // 16 KB
    const int bin = blockIdx.x;
    const int tid = threadIdx.x;
    if (tid < 128) lcnt[tid] = 0;
    __syncthreads();
    int c = bincnt[bin];
    if (c > BINCAP2) c = BINCAP2;
    const uint* buf = binbuf + (size_t)bin * BINCAP2;
    for (int i = tid; i < c; i += 256) {
        uint v = buf[i];
        int ln = v >> 16;
        int pos = atomicAdd(&lcnt[ln], 1);
        if (pos < BUCKET_CAP) lbuck[ln * BUCKET_CAP + pos] = (ushort)(v & 0xffffu);
    }
    __syncthreads();
    const uint4* lb = (const uint4*)lbuck;
    uint4* gb = (uint4*)(bucket + (size_t)bin * 128 * BUCKET_CAP);
    #pragma unroll
    for (int i = tid; i < 128 * BUCKET_CAP / 8; i += 256)
        gb[i] = lb[i];
    if (tid < 128) cnt[bin * 128 + tid] = lcnt[tid];   // true degree (incl. >64 overflow)
}

// ---------- fused gather + MFMA layer ----------
// Block = 32 nodes, 512 threads (8 waves). Wave w gathers rows w*4..w*4+3;
// waves 0..3 then compute the 32x32 output tile at col-quarter w (waves 4..7
// idle through the short MFMA phase — ~4% of block time).
// WHY 512: 1563 blocks x 4 waves could never fill 8192 wave slots (76% static
// ceiling, 50% measured). 8-wave blocks give 4 blocks/CU = 32 waves/CU = 100%
// residency during the gather phase, which is the latency-bound majority.
// Gather: bucket row loaded with ONE wave load, entries broadcast via __shfl.
// CORRECTNESS RULE: every __shfl sits at a wave-uniform point — loop trip
// counts uniform across half-waves; tail predicates only per-lane ops.
// h-half staged to REGISTERS before the gather, ds_write after (T14).
template<int RELU, int POOL>
__global__ __launch_bounds__(512, 8) void layer_fused(
    const ushort* __restrict__ X, const int* __restrict__ cnt,
    const ushort* __restrict__ bucket, const ushort* __restrict__ wb,
    const float* __restrict__ bl, ushort* __restrict__ outb,
    const int* __restrict__ batch, float* __restrict__ pool)
{
    __shared__ ushort sA[32 * LSTR];
    const int tid = threadIdx.x;
    const int lane = tid & 63, w = tid >> 6;          // w in 0..7
    const int n0 = blockIdx.x * 32;
    const int half = lane >> 5, lcol = lane & 31;

    // ---- stage h half (k>=128) into registers; LDS write deferred ----
    const int sr0 = tid >> 4, sk0 = (tid & 15) * 8;   // 512 thr x 1 row-chunk
    bf16x8 st0 = (bf16x8){0,0,0,0,0,0,0,0};
    if (n0 + sr0 < N_NODES) st0 = *(const bf16x8*)(X + (size_t)(n0 + sr0) * DIM + sk0);

    // ---- degree counts for this wave's 4 rows (bucket rows padded to 50048;
    //      pad nodes have cnt==0 so their loops are empty) ----
    const int gn0 = n0 + w * 4;
    int cw = cnt[gn0 + (lane & 3)];

    #define ACC4(u) do { \
        a0 += bf2f((u).x & 0xffff); a1 += bf2f((u).x >> 16); \
        a2 += bf2f((u).y & 0xffff); a3 += bf2f((u).y >> 16); } while (0)

    // ---- gather agg half (k<128): rows in pairs, bucket prefetched ----
    #pragma unroll
    for (int rp = 0; rp < 2; ++rp) {
        int beL[2];
        #pragma unroll
        for (int q = 0; q < 2; ++q)
            beL[q] = (int)bucket[(size_t)(gn0 + rp * 2 + q) * BUCKET_CAP + lane];
        #pragma unroll
        for (int q = 0; q < 2; ++q) {
            const int r4 = rp * 2 + q;
            const int row = w * 4 + r4;
            const int c = __shfl(cw, r4);                 // uniform point
            const int cl = c < BUCKET_CAP ? c : BUCKET_CAP;
            float a0 = 0.f, a1 = 0.f, a2 = 0.f, a3 = 0.f;
            int t = 0;
            // stage 1: 8 entries/half/iter (16 edges, 8 loads in flight).
            for (; 2 * t + 15 < cl; t += 8) {
                int e = 2 * t + half;
                int s0 = __shfl(beL[q], e);
                int s1 = __shfl(beL[q], e + 2);
                int s2 = __shfl(beL[q], e + 4);
                int s3 = __shfl(beL[q], e + 6);
                int s4 = __shfl(beL[q], e + 8);
                int s5 = __shfl(beL[q], e + 10);
                int s6 = __shfl(beL[q], e + 12);
                int s7 = __shfl(beL[q], e + 14);
                uint2 u0 = *(const uint2*)(X + (size_t)s0 * DIM + lcol * 4);
                uint2 u1 = *(const uint2*)(X + (size_t)s1 * DIM + lcol * 4);
                uint2 u2 = *(const uint2*)(X + (size_t)s2 * DIM + lcol * 4);
                uint2 u3 = *(const uint2*)(X + (size_t)s3 * DIM + lcol * 4);
                uint2 u4 = *(const uint2*)(X + (size_t)s4 * DIM + lcol * 4);
                uint2 u5 = *(const uint2*)(X + (size_t)s5 * DIM + lcol * 4);
                uint2 u6 = *(const uint2*)(X + (size_t)s6 * DIM + lcol * 4);
                uint2 u7 = *(const uint2*)(X + (size_t)s7 * DIM + lcol * 4);
                ACC4(u0); ACC4(u1); ACC4(u2); ACC4(u3);
                ACC4(u4); ACC4(u5); ACC4(u6); ACC4(u7);
            }
            // stage 2: 4 entries/half/iter (8 edges, 4 loads in flight)
            for (; 2 * t + 7 < cl; t += 4) {
                int e = 2 * t + half;
                int s0 = __shfl(beL[q], e);
                int s1 = __shfl(beL[q], e + 2);
                int s2 = __shfl(beL[q], e + 4);
                int s3 = __shfl(beL[q], e + 6);
                uint2 u0 = *(const uint2*)(X + (size_t)s0 * DIM + lcol * 4);
                uint2 u1 = *(const uint2*)(X + (size_t)s1 * DIM + lcol * 4);
                uint2 u2 = *(const uint2*)(X + (size_t)s2 * DIM + lcol * 4);
                uint2 u3 = *(const uint2*)(X + (size_t)s3 * DIM + lcol * 4);
                ACC4(u0); ACC4(u1); ACC4(u2); ACC4(u3);
            }
            // tail: uniform trip count T; shfl unconditional (index <= 63),
            // load+accumulate predicated per-lane (no cross-lane op inside).
            const int T = (cl + 1) >> 1;
            for (; t < T; ++t) {
                int e = 2 * t + half;
                int s0 = __shfl(beL[q], e);
                if (e < cl) {
                    uint2 u0 = *(const uint2*)(X + (size_t)s0 * DIM + lcol * 4);
                    ACC4(u0);
                }
            }
            a0 += __shfl_xor(a0, 32);
            a1 += __shfl_xor(a1, 32);
            a2 += __shfl_xor(a2, 32);
            a3 += __shfl_xor(a3, 32);
            if (half == 0) {
                float inv = 1.0f / (float)(c > 0 ? c : 1);
                uint2 o;
                o.x = ((unsigned int)f2bf(a1 * inv) << 16) | f2bf(a0 * inv);
                o.y = ((unsigned int)f2bf(a3 * inv) << 16) | f2bf(a2 * inv);
                *(uint2*)(&sA[row * LSTR + lcol * 4]) = o;
            }
        }
    }
    #undef ACC4

    // ---- deferred h-half LDS write (stage loads long since landed) ----
    *(bf16x8*)(&sA[sr0 * LSTR + DIM + sk0]) = st0;
    __syncthreads();

    // ---- MFMA (waves 0..3): wave w computes rows 0..31 x cols w*32..+31 ----
    if (w < 4) {
        const ushort* wp = wb + (size_t)(w * 32 + (lane & 31)) * KTOT + (lane >> 5) * 8;
        const int arow = lane & 31;
        const int akoff = (lane >> 5) * 8;
        f32x16 acc = {};
        #pragma unroll
        for (int kt = 0; kt < 16; ++kt) {
            bf16x8 a = *(const bf16x8*)(&sA[arow * LSTR + kt * 16 + akoff]);
            bf16x8 bwf = *(const bf16x8*)(wp + kt * 16);
            acc = __builtin_amdgcn_mfma_f32_32x32x16_bf16(a, bwf, acc, 0, 0, 0);
        }

        // C/D map: col=lane&31, row=(reg&3)+8*(reg>>2)+4*(lane>>5)  [m74/m101]
        const int j = w * 32 + (lane & 31);
        const float bias = bl[j];
        if (POOL) {
            // rows ascend with r -> run-flush per graph segment (batch sorted)
            float run = 0.f; int gcur = -1;
            #pragma unroll
            for (int r = 0; r < 16; ++r) {
                int row = (r & 3) + 8 * (r >> 2) + 4 * (lane >> 5);
                int gn = n0 + row;
                if (gn < N_NODES) {
                    float v = acc[r] + bias;
                    int g = batch[gn];
                    if (g != gcur) {
                        if (gcur >= 0) unsafeAtomicAdd(&pool[gcur * DIM + j], run);
                        run = 0.f; gcur = g;
                    }
                    run += v;
                }
            }
            if (gcur >= 0) unsafeAtomicAdd(&pool[gcur * DIM + j], run);
        } else {
            #pragma unroll
            for (int r = 0; r < 16; ++r) {
                int row = (r & 3) + 8 * (r >> 2) + 4 * (lane >> 5);
                int gn = n0 + row;
                if (gn < N_NODES) {
                    float v = acc[r] + bias;
                    if (RELU) v = fmaxf(v, 0.f);
                    outb[(size_t)gn * DIM + j] = f2bf(v);
                }
            }
        }
    }
}

// ---------- pool finalize ----------
__global__ void pool2_kernel(const float* __restrict__ pool, const int* __restrict__ batch,
                             float* __restrict__ out) {
    int g = blockIdx.x;
    int j = threadIdx.x;
    int lo = 0, hi = N_NODES;
    while (lo < hi) { int m = (lo + hi) >> 1; if (batch[m] < g) lo = m + 1; else hi = m; }
    int start = lo;
    lo = start; hi = N_NODES;
    while (lo < hi) { int m = (lo + hi) >> 1; if (batch[m] < g + 1) lo = m + 1; else hi = m; }
    int cnt = lo - start;
    out[g * DIM + j] = pool[g * DIM + j] / (float)(cnt > 0 ? cnt : 1);
}

extern "C" void kernel_launch(void* const* d_in, const int* in_sizes, int n_in,
                              void* d_out, int out_size, void* d_ws, size_t ws_size,
                              hipStream_t stream) {
    const float* x    = (const float*)d_in[0];
    const int*   ei   = (const int*)d_in[1];
    const int*   src  = ei;
    const int*   dst  = ei + N_EDGES;
    const int*   batch = (const int*)d_in[2];
    const float* Wl0 = (const float*)d_in[3];
    const float* bl0 = (const float*)d_in[4];
    const float* Wr0 = (const float*)d_in[5];
    const float* Wl1 = (const float*)d_in[6];
    const float* bl1 = (const float*)d_in[7];
    const float* Wr1 = (const float*)d_in[8];
    const float* Wl2 = (const float*)d_in[9];
    const float* bl2 = (const float*)d_in[10];
    const float* Wr2 = (const float*)d_in[11];
    float* out = (float*)d_out;

    int*    cnt    = (int*)d_ws;                               // 65536 ints
    ushort* bucket = (ushort*)(cnt + 65536);                   // N_NODES_PAD*64 ushorts
    ushort* xb     = bucket + (size_t)N_NODES_PAD * BUCKET_CAP;
    ushort* h1b    = xb + (size_t)N_NODES * DIM;
    ushort* h2b    = h1b + (size_t)N_NODES * DIM;
    ushort* wb     = h2b + (size_t)N_NODES * DIM;              // 3 * 32768 bf16
    float*  pool   = (float*)(wb + 3 * DIM * KTOT);            // 8192 floats
    int*    bincnt = (int*)(pool + N_GRAPHS * DIM);            // NBINS ints
    uint*   binbuf = (uint*)(bincnt + ((NBINS + 63) & ~63));   // NBINS*BINCAP2 uints (4.4 MB)

    castx_kernel<<<(N_NODES * DIM / 4 + 255) / 256, 256, 0, stream>>>(x, xb, bincnt);
    castw_kernel<<<(3 * DIM * KTOT + 255) / 256, 256, 0, stream>>>(Wl0, Wr0, Wl1, Wr1, Wl2, Wr2, wb, pool);
    bin1_kernel<<<BIN1_GRID, BIN1_TPB, 0, stream>>>(src, dst, bincnt, binbuf);
    bin2_kernel<<<NBINS, 256, 0, stream>>>(binbuf, bincnt, bucket, cnt);

    const int lgrid = (N_NODES + 31) / 32;
    layer_fused<1, 0><<<lgrid, 512, 0, stream>>>(xb,  cnt, bucket, wb,          bl0, h1b, batch, pool);
    layer_fused<1, 0><<<lgrid, 512, 0, stream>>>(h1b, cnt, bucket, wb + 32768,  bl1, h2b, batch, pool);
    layer_fused<0, 1><<<lgrid, 512, 0, stream>>>(h2b, cnt, bucket, wb + 65536,  bl2, nullptr, batch, pool);

    pool2_kernel<<<N_GRAPHS, DIM, 0, stream>>>(pool, batch, out);
}

// Round 9
// 243.018 us; speedup vs baseline: 1.0426x; 1.0426x over previous
//
#include <hip/hip_runtime.h>

#define N_NODES 50000
#define N_EDGES 800000
#define DIM 128
#define KTOT 256        // [agg | x] concatenated along k
#define N_GRAPHS 64
#define BUCKET_CAP 64
#define LSTR 264        // LDS A-tile row stride in bf16 (+8 pad)

// edge binning: bin = dst>>6 (64 nodes/bin) -> 782 bin2 blocks (2x parallelism)
#define NBINS 782       // ceil(50000/64)
#define BINCAP2 1408    // per-bin list capacity (mean 1024, +12 sigma)
#define N_NODES_PAD (NBINS * 64)   // 50048 (same padded bucket size as before)

// bin1 geometry: 512 thr x 8 edges = 4096 edges/block -> 196 blocks
#define BIN1_TPB 512
#define BIN1_EPT 8
#define BIN1_EPB (BIN1_TPB * BIN1_EPT)
#define BIN1_GRID ((N_EDGES + BIN1_EPB - 1) / BIN1_EPB)

typedef __attribute__((ext_vector_type(8))) short bf16x8;
typedef __attribute__((ext_vector_type(16))) float f32x16;

__device__ __forceinline__ float bf2f(unsigned int u16) {
    return __uint_as_float(u16 << 16);
}
__device__ __forceinline__ unsigned short f2bf(float f) {
    unsigned int v = __float_as_uint(f);
    unsigned int r = (v + 0x7fffu + ((v >> 16) & 1u)) >> 16;   // RNE
    return (unsigned short)r;
}

// ---------- setup: casts ----------
// also zeros bincnt (must run before bin1_kernel)
__global__ void castx_kernel(const float* __restrict__ x, ushort* __restrict__ xb,
                             int* __restrict__ bincnt) {
    int i = blockIdx.x * blockDim.x + threadIdx.x;   // float4 index
    if (i < NBINS) bincnt[i] = 0;
    if (i >= N_NODES * DIM / 4) return;
    float4 v = ((const float4*)x)[i];
    ushort4 o;
    o.x = f2bf(v.x); o.y = f2bf(v.y); o.z = f2bf(v.z); o.w = f2bf(v.w);
    ((ushort4*)xb)[i] = o;
}

// wb layout per layer: [128 j][256 k] with k<128 = Wl, k>=128 = Wr. Also zeros pool.
__global__ void castw_kernel(const float* __restrict__ Wl0, const float* __restrict__ Wr0,
                             const float* __restrict__ Wl1, const float* __restrict__ Wr1,
                             const float* __restrict__ Wl2, const float* __restrict__ Wr2,
                             ushort* __restrict__ wb, float* __restrict__ pool) {
    int id = blockIdx.x * blockDim.x + threadIdx.x;   // 3*128*256 = 98304
    if (id < N_GRAPHS * DIM) pool[id] = 0.f;
    if (id >= 3 * DIM * KTOT) return;
    int l = id >> 15;
    int r = id & 32767;
    int j = r >> 8, k = r & 255;
    const float* Wl = (l == 0) ? Wl0 : (l == 1) ? Wl1 : Wl2;
    const float* Wr = (l == 0) ? Wr0 : (l == 1) ? Wr1 : Wr2;
    float v = (k < DIM) ? Wl[j * DIM + k] : Wr[j * DIM + k - DIM];
    wb[id] = f2bf(v);
}

// ---------- edge binning phase 1: LDS-ranked block partition ----------
__global__ __launch_bounds__(BIN1_TPB) void bin1_kernel(
    const int* __restrict__ src, const int* __restrict__ dst,
    int* __restrict__ bincnt, uint* __restrict__ binbuf) {
    __shared__ uint hist[NBINS];
    __shared__ uint gbase[NBINS];
    const int tid = threadIdx.x;
    for (int i = tid; i < NBINS; i += BIN1_TPB) hist[i] = 0;
    __syncthreads();

    const int e0 = blockIdx.x * BIN1_EPB + tid * BIN1_EPT;
    uint val[BIN1_EPT];
    int  bin[BIN1_EPT];
    uint rk[BIN1_EPT];

    if (e0 + BIN1_EPT <= N_EDGES) {
        int4 s0 = *(const int4*)(src + e0);
        int4 s1 = *(const int4*)(src + e0 + 4);
        int4 d0 = *(const int4*)(dst + e0);
        int4 d1 = *(const int4*)(dst + e0 + 4);
        int ss[8] = {s0.x, s0.y, s0.z, s0.w, s1.x, s1.y, s1.z, s1.w};
        int dd[8] = {d0.x, d0.y, d0.z, d0.w, d1.x, d1.y, d1.z, d1.w};
        #pragma unroll
        for (int i = 0; i < BIN1_EPT; ++i) {
            bin[i] = dd[i] >> 6;
            val[i] = (uint)ss[i] | ((uint)(dd[i] & 63) << 16);
            rk[i]  = atomicAdd(&hist[bin[i]], 1u);
        }
    } else {
        #pragma unroll
        for (int i = 0; i < BIN1_EPT; ++i) {
            if (e0 + i < N_EDGES) {
                int s = src[e0 + i], d = dst[e0 + i];
                bin[i] = d >> 6;
                val[i] = (uint)s | ((uint)(d & 63) << 16);
                rk[i]  = atomicAdd(&hist[bin[i]], 1u);
            } else {
                bin[i] = -1; val[i] = 0; rk[i] = 0;
            }
        }
    }
    __syncthreads();

    for (int i = tid; i < NBINS; i += BIN1_TPB)
        gbase[i] = (uint)atomicAdd(&bincnt[i], (int)hist[i]);
    __syncthreads();

    #pragma unroll
    for (int i = 0; i < BIN1_EPT; ++i) {
        if (bin[i] >= 0) {
            uint pos = gbase[bin[i]] + rk[i];
            if (pos < BINCAP2)
                binbuf[(size_t)bin[i] * BINCAP2 + pos] = val[i];
        }
    }
}

// ---------- edge binning phase 2: LDS bucket build, coalesced flush ----------
// 64-node bins: 782 blocks (was 391) -> 2x wave supply for this latency-bound
// LDS-atomic replay; 8.2 KB LDS/block.
__global__ __launch_bounds__(256) void bin2_kernel(
    const uint* __restrict__ binbuf, const int* __restrict__ bincnt,
    ushort* __restrict__ bucket, int* __restrict__ cnt) {
    __shared__ int lcnt[64];
    __shared__ ushort lbuck[64 * BUCKET_CAP];   // 8 KB
    const int bin = blockIdx.x;
    const int tid = threadIdx.x;
    if (tid < 64) lcnt[tid] = 0;
    __syncthreads();
    int c = bincnt[bin];
    if (c > BINCAP2) c = BINCAP2;
    const uint* buf = binbuf + (size_t)bin * BINCAP2;
    for (int i = tid; i < c; i += 256) {
        uint v = buf[i];
        int ln = v >> 16;
        int pos = atomicAdd(&lcnt[ln], 1);
        if (pos < BUCKET_CAP) lbuck[ln * BUCKET_CAP + pos] = (ushort)(v & 0xffffu);
    }
    __syncthreads();
    const uint4* lb = (const uint4*)lbuck;
    uint4* gb = (uint4*)(bucket + (size_t)bin * 64 * BUCKET_CAP);
    #pragma unroll
    for (int i = tid; i < 64 * BUCKET_CAP / 8; i += 256)
        gb[i] = lb[i];
    if (tid < 64) cnt[bin * 64 + tid] = lcnt[tid];   // true degree (incl. >64 overflow)
}

// ---------- fused gather + MFMA layer ----------
// EXACT round-7-measured structure (45.0 us, VGPR 28): block = 32 nodes,
// 256 threads (4 waves). Wave w gathers rows w*8..w*8+7 and computes the
// 32x32 output tile at col-quarter w.
// Gather: bucket row loaded with ONE wave load, entries broadcast via __shfl.
// CORRECTNESS RULE: every __shfl sits at a wave-uniform point — loop trip
// counts uniform across half-waves; tail predicates only per-lane ops.
// NOTE (R6-R8 evidence): gather time is pinned at FETCH/1.8 TB/s (compulsory
// per-XCD cold misses of X) — ILP/TLP/load-width changes are all neutral or
// negative. Do not re-try concurrency levers here.
template<int RELU, int POOL>
__global__ __launch_bounds__(256, 8) void layer_fused(
    const ushort* __restrict__ X, const int* __restrict__ cnt,
    const ushort* __restrict__ bucket, const ushort* __restrict__ wb,
    const float* __restrict__ bl, ushort* __restrict__ outb,
    const int* __restrict__ batch, float* __restrict__ pool)
{
    __shared__ ushort sA[32 * LSTR];
    const int tid = threadIdx.x;
    const int lane = tid & 63, w = tid >> 6;          // w in 0..3
    const int n0 = blockIdx.x * 32;
    const int half = lane >> 5, lcol = lane & 31;

    // ---- stage h half (k>=128) into registers; LDS write deferred ----
    const int sr0 = tid >> 4, sk0 = (tid & 15) * 8;           // rows 0..15
    const int sr1 = sr0 + 16;                                  // rows 16..31
    bf16x8 st0 = (bf16x8){0,0,0,0,0,0,0,0}, st1 = st0;
    if (n0 + sr0 < N_NODES) st0 = *(const bf16x8*)(X + (size_t)(n0 + sr0) * DIM + sk0);
    if (n0 + sr1 < N_NODES) st1 = *(const bf16x8*)(X + (size_t)(n0 + sr1) * DIM + sk0);

    // ---- degree counts for this wave's 8 rows (bucket rows padded to 50048) ----
    const int gn0 = n0 + w * 8;
    int cw = cnt[gn0 + (lane & 7)];

    #define ACC4(u) do { \
        a0 += bf2f((u).x & 0xffff); a1 += bf2f((u).x >> 16); \
        a2 += bf2f((u).y & 0xffff); a3 += bf2f((u).y >> 16); } while (0)

    // ---- gather agg half (k<128): rows in pairs, bucket prefetched ----
    for (int rp = 0; rp < 4; ++rp) {
        int beL[2];
        #pragma unroll
        for (int q = 0; q < 2; ++q)
            beL[q] = (int)bucket[(size_t)(gn0 + rp * 2 + q) * BUCKET_CAP + lane];
        #pragma unroll
        for (int q = 0; q < 2; ++q) {
            const int r8 = rp * 2 + q;
            const int row = w * 8 + r8;
            const int c = __shfl(cw, r8);                 // uniform point
            const int cl = c < BUCKET_CAP ? c : BUCKET_CAP;
            float a0 = 0.f, a1 = 0.f, a2 = 0.f, a3 = 0.f;
            int t = 0;
            // stage 1: 8 entries/half/iter (16 edges, 8 loads in flight).
            for (; 2 * t + 15 < cl; t += 8) {
                int e = 2 * t + half;
                int s0 = __shfl(beL[q], e);
                int s1 = __shfl(beL[q], e + 2);
                int s2 = __shfl(beL[q], e + 4);
                int s3 = __shfl(beL[q], e + 6);
                int s4 = __shfl(beL[q], e + 8);
                int s5 = __shfl(beL[q], e + 10);
                int s6 = __shfl(beL[q], e + 12);
                int s7 = __shfl(beL[q], e + 14);
                uint2 u0 = *(const uint2*)(X + (size_t)s0 * DIM + lcol * 4);
                uint2 u1 = *(const uint2*)(X + (size_t)s1 * DIM + lcol * 4);
                uint2 u2 = *(const uint2*)(X + (size_t)s2 * DIM + lcol * 4);
                uint2 u3 = *(const uint2*)(X + (size_t)s3 * DIM + lcol * 4);
                uint2 u4 = *(const uint2*)(X + (size_t)s4 * DIM + lcol * 4);
                uint2 u5 = *(const uint2*)(X + (size_t)s5 * DIM + lcol * 4);
                uint2 u6 = *(const uint2*)(X + (size_t)s6 * DIM + lcol * 4);
                uint2 u7 = *(const uint2*)(X + (size_t)s7 * DIM + lcol * 4);
                ACC4(u0); ACC4(u1); ACC4(u2); ACC4(u3);
                ACC4(u4); ACC4(u5); ACC4(u6); ACC4(u7);
            }
            // stage 2: 4 entries/half/iter (8 edges, 4 loads in flight)
            for (; 2 * t + 7 < cl; t += 4) {
                int e = 2 * t + half;
                int s0 = __shfl(beL[q], e);
                int s1 = __shfl(beL[q], e + 2);
                int s2 = __shfl(beL[q], e + 4);
                int s3 = __shfl(beL[q], e + 6);
                uint2 u0 = *(const uint2*)(X + (size_t)s0 * DIM + lcol * 4);
                uint2 u1 = *(const uint2*)(X + (size_t)s1 * DIM + lcol * 4);
                uint2 u2 = *(const uint2*)(X + (size_t)s2 * DIM + lcol * 4);
                uint2 u3 = *(const uint2*)(X + (size_t)s3 * DIM + lcol * 4);
                ACC4(u0); ACC4(u1); ACC4(u2); ACC4(u3);
            }
            // tail: uniform trip count T; shfl unconditional (index <= 63),
            // load+accumulate predicated per-lane (no cross-lane op inside).
            const int T = (cl + 1) >> 1;
            for (; t < T; ++t) {
                int e = 2 * t + half;
                int s0 = __shfl(beL[q], e);
                if (e < cl) {
                    uint2 u0 = *(const uint2*)(X + (size_t)s0 * DIM + lcol * 4);
                    ACC4(u0);
                }
            }
            a0 += __shfl_xor(a0, 32);
            a1 += __shfl_xor(a1, 32);
            a2 += __shfl_xor(a2, 32);
            a3 += __shfl_xor(a3, 32);
            if (half == 0) {
                float inv = 1.0f / (float)(c > 0 ? c : 1);
                uint2 o;
                o.x = ((unsigned int)f2bf(a1 * inv) << 16) | f2bf(a0 * inv);
                o.y = ((unsigned int)f2bf(a3 * inv) << 16) | f2bf(a2 * inv);
                *(uint2*)(&sA[row * LSTR + lcol * 4]) = o;
            }
        }
    }
    #undef ACC4

    // ---- deferred h-half LDS write (stage loads long since landed) ----
    *(bf16x8*)(&sA[sr0 * LSTR + DIM + sk0]) = st0;
    *(bf16x8*)(&sA[sr1 * LSTR + DIM + sk0]) = st1;
    __syncthreads();

    // ---- MFMA: wave w computes rows 0..31 x cols w*32..w*32+31 ----
    // W frags loaded on the fly (L2-hot): lane l needs W[w*32+(l&31)][kt*16+(l>>5)*8..]
    const ushort* wp = wb + (size_t)(w * 32 + (lane & 31)) * KTOT + (lane >> 5) * 8;
    const int arow = lane & 31;
    const int akoff = (lane >> 5) * 8;
    f32x16 acc = {};
    #pragma unroll
    for (int kt = 0; kt < 16; ++kt) {
        bf16x8 a = *(const bf16x8*)(&sA[arow * LSTR + kt * 16 + akoff]);
        bf16x8 bwf = *(const bf16x8*)(wp + kt * 16);
        acc = __builtin_amdgcn_mfma_f32_32x32x16_bf16(a, bwf, acc, 0, 0, 0);
    }

    // C/D map: col=lane&31, row=(reg&3)+8*(reg>>2)+4*(lane>>5)  [m74/m101]
    const int j = w * 32 + (lane & 31);
    const float bias = bl[j];
    if (POOL) {
        // rows ascend with r -> run-flush per graph segment (batch sorted)
        float run = 0.f; int gcur = -1;
        #pragma unroll
        for (int r = 0; r < 16; ++r) {
            int row = (r & 3) + 8 * (r >> 2) + 4 * (lane >> 5);
            int gn = n0 + row;
            if (gn < N_NODES) {
                float v = acc[r] + bias;
                int g = batch[gn];
                if (g != gcur) {
                    if (gcur >= 0) unsafeAtomicAdd(&pool[gcur * DIM + j], run);
                    run = 0.f; gcur = g;
                }
                run += v;
            }
        }
        if (gcur >= 0) unsafeAtomicAdd(&pool[gcur * DIM + j], run);
    } else {
        #pragma unroll
        for (int r = 0; r < 16; ++r) {
            int row = (r & 3) + 8 * (r >> 2) + 4 * (lane >> 5);
            int gn = n0 + row;
            if (gn < N_NODES) {
                float v = acc[r] + bias;
                if (RELU) v = fmaxf(v, 0.f);
                outb[(size_t)gn * DIM + j] = f2bf(v);
            }
        }
    }
}

// ---------- pool finalize ----------
__global__ void pool2_kernel(const float* __restrict__ pool, const int* __restrict__ batch,
                             float* __restrict__ out) {
    int g = blockIdx.x;
    int j = threadIdx.x;
    int lo = 0, hi = N_NODES;
    while (lo < hi) { int m = (lo + hi) >> 1; if (batch[m] < g) lo = m + 1; else hi = m; }
    int start = lo;
    lo = start; hi = N_NODES;
    while (lo < hi) { int m = (lo + hi) >> 1; if (batch[m] < g + 1) lo = m + 1; else hi = m; }
    int cnt = lo - start;
    out[g * DIM + j] = pool[g * DIM + j] / (float)(cnt > 0 ? cnt : 1);
}

extern "C" void kernel_launch(void* const* d_in, const int* in_sizes, int n_in,
                              void* d_out, int out_size, void* d_ws, size_t ws_size,
                              hipStream_t stream) {
    const float* x    = (const float*)d_in[0];
    const int*   ei   = (const int*)d_in[1];
    const int*   src  = ei;
    const int*   dst  = ei + N_EDGES;
    const int*   batch = (const int*)d_in[2];
    const float* Wl0 = (const float*)d_in[3];
    const float* bl0 = (const float*)d_in[4];
    const float* Wr0 = (const float*)d_in[5];
    const float* Wl1 = (const float*)d_in[6];
    const float* bl1 = (const float*)d_in[7];
    const float* Wr1 = (const float*)d_in[8];
    const float* Wl2 = (const float*)d_in[9];
    const float* bl2 = (const float*)d_in[10];
    const float* Wr2 = (const float*)d_in[11];
    float* out = (float*)d_out;

    int*    cnt    = (int*)d_ws;                               // 65536 ints
    ushort* bucket = (ushort*)(cnt + 65536);                   // N_NODES_PAD*64 ushorts
    ushort* xb     = bucket + (size_t)N_NODES_PAD * BUCKET_CAP;
    ushort* h1b    = xb + (size_t)N_NODES * DIM;
    ushort* h2b    = h1b + (size_t)N_NODES * DIM;
    ushort* wb     = h2b + (size_t)N_NODES * DIM;              // 3 * 32768 bf16
    float*  pool   = (float*)(wb + 3 * DIM * KTOT);            // 8192 floats
    int*    bincnt = (int*)(pool + N_GRAPHS * DIM);            // NBINS ints
    uint*   binbuf = (uint*)(bincnt + ((NBINS + 63) & ~63));   // NBINS*BINCAP2 uints (4.4 MB)

    castx_kernel<<<(N_NODES * DIM / 4 + 255) / 256, 256, 0, stream>>>(x, xb, bincnt);
    castw_kernel<<<(3 * DIM * KTOT + 255) / 256, 256, 0, stream>>>(Wl0, Wr0, Wl1, Wr1, Wl2, Wr2, wb, pool);
    bin1_kernel<<<BIN1_GRID, BIN1_TPB, 0, stream>>>(src, dst, bincnt, binbuf);
    bin2_kernel<<<NBINS, 256, 0, stream>>>(binbuf, bincnt, bucket, cnt);

    const int lgrid = (N_NODES + 31) / 32;
    layer_fused<1, 0><<<lgrid, 256, 0, stream>>>(xb,  cnt, bucket, wb,          bl0, h1b, batch, pool);
    layer_fused<1, 0><<<lgrid, 256, 0, stream>>>(h1b, cnt, bucket, wb + 32768,  bl1, h2b, batch, pool);
    layer_fused<0, 1><<<lgrid, 256, 0, stream>>>(h2b, cnt, bucket, wb + 65536,  bl2, nullptr, batch, pool);

    pool2_kernel<<<N_GRAPHS, DIM, 0, stream>>>(pool, batch, out);
}